// Round 2
// 264.030 us; speedup vs baseline: 1.0136x; 1.0136x over previous
//
#include <hip/hip_runtime.h>
#include <math.h>

// NSVQ: N=262144 rows, D=64, K=1024 codebooks.
// d_out (fp32): [N*D] quantized | [1] perplexity | [K] counts_new.
//
// v3: chunked + double-buffered. Codebook as f16 hi/lo of -2c (effective
// 22-bit mantissa -> distance error ~1e-7, better than old bf16 scheme's
// 1e-5 which passed at absmax 2.0). 64-code chunks (16 KB), 2 LDS buffers
// (32 KB total) -> 5 blocks/CU by LDS; stage of chunk c+1 is issued BEFORE
// compute of chunk c, single barrier per chunk (m97 pattern) so the
// vmcnt drain hides under ~230 cyc of MFMA and independent blocks stagger
// across each other's barriers. Exact fp32 argmin compare (no key packing).

#define NROWS 262144
#define DIM 64
#define KCODES 1024
#define ND ((size_t)NROWS * DIM)

typedef __attribute__((ext_vector_type(8))) _Float16 f16x8;  // 4 VGPRs
typedef __attribute__((ext_vector_type(4))) float f32x4;

typedef const __attribute__((address_space(1))) void* as1p;
typedef __attribute__((address_space(3))) void* as3p;
__device__ inline void gl_lds16(const void* g, void* l) {
    __builtin_amdgcn_global_load_lds((as1p)g, (as3p)l, 16, 0, 0);
}

// --- prep: swizzled f16 hi/lo of -2c + fp32 norms -----------------------
// cbs layout (halfs): 64-code chunk c0=k>>6 (8192 halfs = 16 KB each):
//   hi unit (u=j>>3, c=k&63) at c0*8192 + u*512 + c*8 ; lo at +4096
__global__ __launch_bounds__(256) void nsvq_prep(
    const float* __restrict__ cb, _Float16* __restrict__ cbs,
    float* __restrict__ cnorm)
{
    const int tid = blockIdx.x * 256 + threadIdx.x;   // 8192 total
    const int k = tid >> 3;
    const int u = tid & 7;
    const float* p = cb + (size_t)k * DIM + u * 8;
    float4 f0 = *(const float4*)p;
    float4 f1 = *(const float4*)(p + 4);
    float fv[8] = {f0.x, f0.y, f0.z, f0.w, f1.x, f1.y, f1.z, f1.w};

    float s = 0.f;
    f16x8 hv, lv;
#pragma unroll
    for (int j = 0; j < 8; ++j) {
        s = fmaf(fv[j], fv[j], s);
        float m2 = -2.0f * fv[j];
        _Float16 h = (_Float16)m2;
        hv[j] = h;
        lv[j] = (_Float16)(m2 - (float)h);
    }
#pragma unroll
    for (int o = 1; o < 8; o <<= 1) s += __shfl_xor(s, o, 64);

    const size_t base = (size_t)(k >> 6) * 8192 + (size_t)u * 512 + (size_t)(k & 63) * 8;
    *(f16x8*)(cbs + base) = hv;
    *(f16x8*)(cbs + base + 4096) = lv;
    if (u == 0) cnorm[k] = s;
}

// --- fused main ---------------------------------------------------------
// block = 4 waves = 128 rows; wave = 32 rows (2 rowsets of 16).
// lane = (q = dim-octet 0..3, n = row/code-col 0..15).
// LDS = 2 x 16 KB chunk buffers; 16 chunks of 64 codes.
__global__ __launch_bounds__(256, 4) void nsvq_fused(
    const float* __restrict__ x, const float* __restrict__ rv,
    const _Float16* __restrict__ cbs, const float* __restrict__ cnorm,
    float* __restrict__ out, unsigned int* __restrict__ counts)
{
    __shared__ _Float16 lds[16384];   // 32 KB

    const int tid  = threadIdx.x;
    const int lane = tid & 63;
    const int wave = tid >> 6;
    const int q    = lane >> 4;
    const int n    = lane & 15;
    const int wBase = blockIdx.x * 128 + wave * 32;

    // ---- stage chunk 0 (issue first so it overlaps the x-frag build) ----
#pragma unroll
    for (int r = 0; r < 4; ++r) {
        const int off = (r * 256 + tid) * 8;     // halfs, lane-contiguous 16 B
        gl_lds16(cbs + off, lds + off);
    }

    // ---- A: x rows -> f16 hi/lo frags + ||x||^2 (fp32 exact) ----
    f16x8 ah[2][2], al[2][2];
    float xx[2];
#pragma unroll
    for (int s = 0; s < 2; ++s) {
        const int row = wBase + s * 16 + n;
        const float* px = x + (size_t)row * DIM + q * 8;
        float acc = 0.f;
#pragma unroll
        for (int c2 = 0; c2 < 2; ++c2) {
            float4 g0 = *(const float4*)(px + c2 * 32);
            float4 g1 = *(const float4*)(px + c2 * 32 + 4);
            float fv[8] = {g0.x, g0.y, g0.z, g0.w, g1.x, g1.y, g1.z, g1.w};
#pragma unroll
            for (int j = 0; j < 8; ++j) {
                float f = fv[j];
                acc = fmaf(f, f, acc);
                _Float16 h = (_Float16)f;
                ah[s][c2][j] = h;
                al[s][c2][j] = (_Float16)(f - (float)h);
            }
        }
        acc += __shfl_xor(acc, 16, 64);
        acc += __shfl_xor(acc, 32, 64);
        xx[s] = acc;
    }

    float cn_cur[4], cn_nxt[4];
#pragma unroll
    for (int t = 0; t < 4; ++t) cn_cur[t] = cnorm[t * 16 + n];

    float best[2][4];
    int   bidx[2][4];
#pragma unroll
    for (int s = 0; s < 2; ++s)
#pragma unroll
        for (int r = 0; r < 4; ++r) { best[s][r] = 3.4e38f; bidx[s][r] = 0; }

    __syncthreads();   // chunk 0 staged (compiler drains vmcnt here)

    auto compute_chunk = [&](int b, int cbase) {
        const _Float16* buf = lds + b * 8192;
#pragma unroll
        for (int t = 0; t < 4; ++t) {
            const int ci = (t * 16 + n) * 8;
            f16x8 bh0 = *(const f16x8*)(buf + q * 512 + ci);
            f16x8 bh1 = *(const f16x8*)(buf + (q + 4) * 512 + ci);
            f16x8 bl0 = *(const f16x8*)(buf + 4096 + q * 512 + ci);
            f16x8 bl1 = *(const f16x8*)(buf + 4096 + (q + 4) * 512 + ci);
            const int code = cbase + t * 16 + n;
#pragma unroll
            for (int s = 0; s < 2; ++s) {
                f32x4 a = {cn_cur[t], cn_cur[t], cn_cur[t], cn_cur[t]};  // ||c||^2
                a = __builtin_amdgcn_mfma_f32_16x16x32_f16(ah[s][0], bh0, a, 0, 0, 0);
                a = __builtin_amdgcn_mfma_f32_16x16x32_f16(ah[s][1], bh1, a, 0, 0, 0);
                a = __builtin_amdgcn_mfma_f32_16x16x32_f16(al[s][0], bh0, a, 0, 0, 0);
                a = __builtin_amdgcn_mfma_f32_16x16x32_f16(al[s][1], bh1, a, 0, 0, 0);
                a = __builtin_amdgcn_mfma_f32_16x16x32_f16(ah[s][0], bl0, a, 0, 0, 0);
                a = __builtin_amdgcn_mfma_f32_16x16x32_f16(ah[s][1], bl1, a, 0, 0, 0);
#pragma unroll
                for (int r = 0; r < 4; ++r) {
                    if (a[r] < best[s][r]) { best[s][r] = a[r]; bidx[s][r] = code; }
                }
            }
        }
    };

    for (int c = 0; c < 15; ++c) {
        const int b = c & 1;
        // issue next-chunk stage + cnorm prefetch BEFORE computing current
        {
            const _Float16* src = cbs + (size_t)(c + 1) * 8192;
            _Float16* dst = lds + (b ^ 1) * 8192;
#pragma unroll
            for (int r = 0; r < 4; ++r) {
                const int off = (r * 256 + tid) * 8;
                gl_lds16(src + off, dst + off);
            }
#pragma unroll
            for (int t = 0; t < 4; ++t) cn_nxt[t] = cnorm[(c + 1) * 64 + t * 16 + n];
        }
        compute_chunk(b, c * 64);
        __syncthreads();   // drains the prefetch; everyone done reading buf b
#pragma unroll
        for (int t = 0; t < 4; ++t) cn_cur[t] = cn_nxt[t];
    }
    compute_chunk(1, 15 * 64);   // last chunk, no prefetch, no barrier needed

    // ---- cross-lane argmin over the 16 code-lanes ----
#pragma unroll
    for (int o = 1; o < 16; o <<= 1) {
#pragma unroll
        for (int s = 0; s < 2; ++s)
#pragma unroll
            for (int r = 0; r < 4; ++r) {
                float od = __shfl_xor(best[s][r], o, 64);
                int   ok = __shfl_xor(bidx[s][r], o, 64);
                if (od < best[s][r] || (od == best[s][r] && ok < bidx[s][r])) {
                    best[s][r] = od; bidx[s][r] = ok;
                }
            }
    }
    // lane (q,*) now holds winners for rows s*16 + q*4 + r.
    if (n == 0) {
#pragma unroll
        for (int s = 0; s < 2; ++s)
#pragma unroll
            for (int r = 0; r < 4; ++r) atomicAdd(&counts[bidx[s][r]], 1u);
    }

    // ---- route winner dist to row lanes via shuffle ----
    const int src = ((n >> 2) << 4) | n;
#pragma unroll
    for (int s = 0; s < 2; ++s) {
        float w0 = __shfl(best[s][0], src, 64);
        float w1 = __shfl(best[s][1], src, 64);
        float w2 = __shfl(best[s][2], src, 64);
        float w3 = __shfl(best[s][3], src, 64);
        float wa = (n & 1) ? w1 : w0;
        float wb = (n & 1) ? w3 : w2;
        float dmin = (n & 2) ? wb : wa;

        float res2 = xx[s] + dmin;
        if (res2 < 0.f) res2 = 0.f;
        const float resn = sqrtf(res2);

        const int row = wBase + s * 16 + n;
        const float* pr = rv + (size_t)row * DIM + q * 8;
        float rvf[16];
        float rr = 0.f;
#pragma unroll
        for (int c2 = 0; c2 < 2; ++c2) {
            float4 g0 = *(const float4*)(pr + c2 * 32);
            float4 g1 = *(const float4*)(pr + c2 * 32 + 4);
            rvf[c2 * 8 + 0] = g0.x; rvf[c2 * 8 + 1] = g0.y;
            rvf[c2 * 8 + 2] = g0.z; rvf[c2 * 8 + 3] = g0.w;
            rvf[c2 * 8 + 4] = g1.x; rvf[c2 * 8 + 5] = g1.y;
            rvf[c2 * 8 + 6] = g1.z; rvf[c2 * 8 + 7] = g1.w;
#pragma unroll
            for (int j = 0; j < 8; ++j) rr = fmaf(rvf[c2 * 8 + j], rvf[c2 * 8 + j], rr);
        }
        rr += __shfl_xor(rr, 16, 64);
        rr += __shfl_xor(rr, 32, 64);
        const float scale = resn / (sqrtf(rr) + 1e-12f);

        // x reconstructed from f16 hi+lo (error ~|x|*2^-23)
        float* po = out + (size_t)row * DIM + q * 8;
#pragma unroll
        for (int c2 = 0; c2 < 2; ++c2) {
            float4 o0, o1;
            o0.x = fmaf(scale, rvf[c2 * 8 + 0], (float)ah[s][c2][0] + (float)al[s][c2][0]);
            o0.y = fmaf(scale, rvf[c2 * 8 + 1], (float)ah[s][c2][1] + (float)al[s][c2][1]);
            o0.z = fmaf(scale, rvf[c2 * 8 + 2], (float)ah[s][c2][2] + (float)al[s][c2][2]);
            o0.w = fmaf(scale, rvf[c2 * 8 + 3], (float)ah[s][c2][3] + (float)al[s][c2][3]);
            o1.x = fmaf(scale, rvf[c2 * 8 + 4], (float)ah[s][c2][4] + (float)al[s][c2][4]);
            o1.y = fmaf(scale, rvf[c2 * 8 + 5], (float)ah[s][c2][5] + (float)al[s][c2][5]);
            o1.z = fmaf(scale, rvf[c2 * 8 + 6], (float)ah[s][c2][6] + (float)al[s][c2][6]);
            o1.w = fmaf(scale, rvf[c2 * 8 + 7], (float)ah[s][c2][7] + (float)al[s][c2][7]);
            *(float4*)(po + c2 * 32) = o0;
            *(float4*)(po + c2 * 32 + 4) = o1;
        }
    }
}

// --- finalize: perplexity + counts output -------------------------------
__global__ void nsvq_finalize(const unsigned int* __restrict__ counts,
                              const int* __restrict__ used,
                              float* __restrict__ out)
{
    const int k = threadIdx.x;  // 1024 threads
    const unsigned c = counts[k];
    float avg = (float)c * (1.0f / (float)NROWS);
    float term = (c > 0) ? (-avg * logf(avg + 1e-12f)) : 0.0f;

    float v = term;
#pragma unroll
    for (int o = 32; o > 0; o >>= 1) v += __shfl_down(v, o, 64);

    __shared__ float partial[16];
    if ((threadIdx.x & 63) == 0) partial[threadIdx.x >> 6] = v;
    __syncthreads();

    if (threadIdx.x < 64) {
        float s = (threadIdx.x < 16) ? partial[threadIdx.x] : 0.0f;
#pragma unroll
        for (int o = 32; o > 0; o >>= 1) s += __shfl_down(s, o, 64);
        if (threadIdx.x == 0) out[ND] = expf(s);
    }
    out[ND + 1 + k] = (float)(c + (unsigned)used[k]);
}

extern "C" void kernel_launch(void* const* d_in, const int* in_sizes, int n_in,
                              void* d_out, int out_size, void* d_ws, size_t ws_size,
                              hipStream_t stream) {
    const float* x    = (const float*)d_in[0];
    const float* rv   = (const float*)d_in[1];
    const float* cb   = (const float*)d_in[2];
    const int*   used = (const int*)d_in[3];
    float* out = (float*)d_out;

    char* ws = (char*)d_ws;
    unsigned int* counts = (unsigned int*)ws;                 // 4 KB
    float*        cnorm  = (float*)(ws + 4096);               // 4 KB
    _Float16*     cbs    = (_Float16*)(ws + 8192);            // 256 KB f16 hi/lo -2c

    hipMemsetAsync(counts, 0, KCODES * sizeof(unsigned int), stream);
    nsvq_prep<<<KCODES * 8 / 256, 256, 0, stream>>>(cb, cbs, cnorm);
    nsvq_fused<<<NROWS / 128, 256, 0, stream>>>(x, rv, cbs, cnorm, out, counts);
    nsvq_finalize<<<1, KCODES, 0, stream>>>(counts, used, out);
}